// Round 8
// baseline (341.863 us; speedup 1.0000x reference)
//
#include <hip/hip_runtime.h>
#include <hip/hip_bf16.h>
#include <math.h>

typedef __attribute__((ext_vector_type(8))) short bf16x8;   // 8 bf16 in 4 VGPRs
typedef __attribute__((ext_vector_type(4))) float f32x4;
typedef unsigned short ushort;

#define MFMA16(a, b, c) __builtin_amdgcn_mfma_f32_16x16x32_bf16((a), (b), (c), 0, 0, 0)

constexpr int BB = 8, CC = 64, NN = 4096;
constexpr float LOG2E = 1.4426950408889634f;

__device__ __forceinline__ short f2bf(float f) {
    return __builtin_bit_cast(short, __float2bfloat16(f));   // RNE f32->bf16
}

// ---------------------------------------------------------------------------
// Pass 1 (v2): K/Q/V projections -> bf16.  512 threads, 8 positions/thread
// (was 256 thr x 16 pos: halves each thread's dependency chain, doubles
// waves/CU to 16).  Layouts: Kt/Qt [b][n][c] (Kt pre-scaled by log2e),
// V [b][o][m].  All global stores coalesced bf16x8.
// ---------------------------------------------------------------------------
__global__ __launch_bounds__(512, 4) void proj_kernel(
    const float* __restrict__ x,
    const float* __restrict__ Wk, const float* __restrict__ bk,
    const float* __restrict__ Wq, const float* __restrict__ bq,
    const float* __restrict__ Wv, const float* __restrict__ bv,
    ushort* __restrict__ Kt, ushort* __restrict__ Qt, ushort* __restrict__ Vo)
{
    __shared__ float xs[64][64];    // [c][pos]
    __shared__ float wkt[64][65];   // [c][o]; reused as K-transpose staging
    __shared__ float wqt[64][65];   // [c][o]; reused as Q-transpose staging
    __shared__ float wvt[64][65];

    const int t   = threadIdx.x;
    const int bid = ((blockIdx.x & 7) << 6) + (blockIdx.x >> 3);  // XCD x -> batch x
    const int b   = bid >> 6;
    const int n0  = (bid & 63) << 6;
    const int o   = t >> 3;   // 0..63 channel
    const int f   = t & 7;    // 0..7 position-octet

    {   // stage x tile (two float4 per thread, coalesced)
        const float* src = x + ((size_t)b * CC + o) * NN + n0 + f * 8;
        *(float4*)&xs[o][f * 8]     = ((const float4*)src)[0];
        *(float4*)&xs[o][f * 8 + 4] = ((const float4*)src)[1];
    }
    {   // stage W transposed: wt[c][o] = W[o][c]
        const float* sk = Wk + o * 64 + f * 8;
        const float* sq = Wq + o * 64 + f * 8;
        const float* sv = Wv + o * 64 + f * 8;
        #pragma unroll
        for (int j = 0; j < 8; ++j) {
            wkt[f * 8 + j][o] = sk[j];
            wqt[f * 8 + j][o] = sq[j];
            wvt[f * 8 + j][o] = sv[j];
        }
    }
    __syncthreads();

    float ak[8], aq[8], av[8];
    {
        const float bkv = bk[o], bqv = bq[o], bvv = bv[o];
        #pragma unroll
        for (int j = 0; j < 8; ++j) { ak[j] = bkv; aq[j] = bqv; av[j] = bvv; }
    }

    #pragma unroll 8
    for (int c = 0; c < 64; ++c) {
        const float wk = wkt[c][o];
        const float wq = wqt[c][o];
        const float wv = wvt[c][o];
        const float4 x0 = *(const float4*)&xs[c][f * 8];
        const float4 x1 = *(const float4*)&xs[c][f * 8 + 4];
        ak[0]=fmaf(wk,x0.x,ak[0]); ak[1]=fmaf(wk,x0.y,ak[1]);
        ak[2]=fmaf(wk,x0.z,ak[2]); ak[3]=fmaf(wk,x0.w,ak[3]);
        ak[4]=fmaf(wk,x1.x,ak[4]); ak[5]=fmaf(wk,x1.y,ak[5]);
        ak[6]=fmaf(wk,x1.z,ak[6]); ak[7]=fmaf(wk,x1.w,ak[7]);
        aq[0]=fmaf(wq,x0.x,aq[0]); aq[1]=fmaf(wq,x0.y,aq[1]);
        aq[2]=fmaf(wq,x0.z,aq[2]); aq[3]=fmaf(wq,x0.w,aq[3]);
        aq[4]=fmaf(wq,x1.x,aq[4]); aq[5]=fmaf(wq,x1.y,aq[5]);
        aq[6]=fmaf(wq,x1.z,aq[6]); aq[7]=fmaf(wq,x1.w,aq[7]);
        av[0]=fmaf(wv,x0.x,av[0]); av[1]=fmaf(wv,x0.y,av[1]);
        av[2]=fmaf(wv,x0.z,av[2]); av[3]=fmaf(wv,x0.w,av[3]);
        av[4]=fmaf(wv,x1.x,av[4]); av[5]=fmaf(wv,x1.y,av[5]);
        av[6]=fmaf(wv,x1.z,av[6]); av[7]=fmaf(wv,x1.w,av[7]);
    }

    // V: coalesced bf16 store [b][o][m]
    {
        bf16x8 v0;
        #pragma unroll
        for (int j = 0; j < 8; ++j) v0[j] = f2bf(av[j]);
        *(bf16x8*)(Vo + ((size_t)b * CC + o) * NN + n0 + f * 8) = v0;
    }

    // K/Q transpose via padded LDS (weights dead), then coalesced stores
    __syncthreads();
    #pragma unroll
    for (int j = 0; j < 8; ++j) {
        wkt[f * 8 + j][o] = ak[j] * LOG2E;   // [pos][c]
        wqt[f * 8 + j][o] = aq[j];
    }
    __syncthreads();
    {
        const int n = t >> 3;   // position row
        const int g = t & 7;    // 8-channel segment
        bf16x8 kv, qv;
        #pragma unroll
        for (int j = 0; j < 8; ++j) {
            kv[j] = f2bf(wkt[n][g * 8 + j]);
            qv[j] = f2bf(wqt[n][g * 8 + j]);
        }
        const size_t base = ((size_t)b * NN + n0 + n) * CC + g * 8;
        *(bf16x8*)(Kt + base) = kv;
        *(bf16x8*)(Qt + base) = qv;
    }
}

// ---------------------------------------------------------------------------
// Pass 2 (v3): flash attention (no-max softmax; scores bounded ~2^12 in log2
// domain) + fused Wl projection + residual.
// 1024 blocks (b, 32-row n-tile), 8 warps: warp w -> (wr = w>>2: 16-row
// fragment group, ms = w&3: m-quarter).  P stored in LDS as bf16 (2KB/warp,
// XOR-swizzled), unioned with the 4KB f32 O-park slab -> 33KB LDS total,
// 4 blocks/CU, ~24+ waves/CU (vs 7 in round 7: latency-bound, both pipes <26%).
// ---------------------------------------------------------------------------
__global__ __launch_bounds__(512, 8) void attn_kernel(
    const ushort* __restrict__ Kt, const ushort* __restrict__ Qt,
    const ushort* __restrict__ V,  const float* __restrict__ x,
    const float* __restrict__ Wl,  const float* __restrict__ bl,
    float* __restrict__ out)
{
    __shared__ float slab[8][1024];  // per-warp: P(bf16, first 2KB) then O-park(f32)
    __shared__ float lsl[8][16];     // per-warp row sums l

    const int t    = threadIdx.x;
    const int w    = t >> 6;         // 0..7
    const int wr   = w >> 2;         // 0..1 : 16-row fragment group
    const int ms   = w & 3;          // 0..3 : m-quarter
    const int l    = t & 63;
    const int lr   = l & 15;
    const int lh   = l >> 4;
    const int swz  = (lr & 7) << 2;  // f32-index XOR for row=lr slab reads
    const int pswz = (lr & 7) << 3;  // ushort-index XOR for row=lr P reads
    const int bid  = ((blockIdx.x & 7) << 7) + (blockIdx.x >> 3);  // XCD swizzle
    const int b    = bid >> 7;
    const int n0   = (bid & 127) << 5;
    const int nrow0 = n0 + wr * 16;

    ushort* Pb = (ushort*)&slab[w][0];  // 16x64 bf16, swizzled

    // K A-fragments (row = lr, k = 8*lh..+7 / +32), held all kernel
    bf16x8 ka0, ka1;
    {
        const ushort* kp = Kt + ((size_t)b * NN + nrow0 + lr) * CC + lh * 8;
        ka0 = *(const bf16x8*)kp;
        ka1 = *(const bf16x8*)(kp + 32);
    }

    f32x4 oa[4];
    #pragma unroll
    for (int os = 0; os < 4; ++os) oa[os] = f32x4{0.f, 0.f, 0.f, 0.f};
    float lacc[4] = {0.f, 0.f, 0.f, 0.f};

    const ushort* Qb = Qt + (size_t)b * NN * CC;
    const ushort* Vb = V + (size_t)b * CC * NN;

    for (int it = 0; it < 16; ++it) {
        const int m0 = (ms << 10) + (it << 6);

        // S = K^T Q per 16-col subtile -> exp2 -> bf16 P (cvt BEFORE the
        // write: off the read-dependency path)
        #pragma unroll
        for (int s = 0; s < 4; ++s) {
            const ushort* qp = Qb + (size_t)(m0 + s * 16 + lr) * CC + lh * 8;
            const bf16x8 q0 = *(const bf16x8*)qp;
            const bf16x8 q1 = *(const bf16x8*)(qp + 32);
            f32x4 a = f32x4{0.f, 0.f, 0.f, 0.f};
            a = MFMA16(ka0, q0, a);
            a = MFMA16(ka1, q1, a);
            #pragma unroll
            for (int r = 0; r < 4; ++r) {
                const int row = 4 * lh + r;
                const float p = exp2f(a[r]);
                lacc[r] += p;
                Pb[(row * 64 + (lr + 16 * s)) ^ ((row & 7) << 3)] = (ushort)f2bf(p);
            }
        }

        // P A-fragments: row = lr, k = 8*lh (+32); single b128 each
        const bf16x8 pa0 = *(const bf16x8*)&Pb[lr * 64 + ((8 * lh) ^ pswz)];
        const bf16x8 pa1 = *(const bf16x8*)&Pb[lr * 64 + ((8 * lh + 32) ^ pswz)];

        // O += P * V^T
        #pragma unroll
        for (int os = 0; os < 4; ++os) {
            const ushort* vp = Vb + (size_t)(os * 16 + lr) * NN + m0 + lh * 8;
            const bf16x8 v0 = *(const bf16x8*)vp;
            const bf16x8 v1 = *(const bf16x8*)(vp + 32);
            oa[os] = MFMA16(pa0, v0, oa[os]);
            oa[os] = MFMA16(pa1, v1, oa[os]);
        }
    }

    // reduce l over the 16 lr lanes
    #pragma unroll
    for (int r = 0; r < 4; ++r) {
        float v = lacc[r];
        v += __shfl_xor(v, 1);
        v += __shfl_xor(v, 2);
        v += __shfl_xor(v, 4);
        v += __shfl_xor(v, 8);
        lacc[r] = v;
    }
    if (lr == 0) {
        #pragma unroll
        for (int r = 0; r < 4; ++r) lsl[w][4 * lh + r] = lacc[r];
    }

    // park partial O (f32, swizzled D-layout; P region is dead now)
    #pragma unroll
    for (int os = 0; os < 4; ++os)
        #pragma unroll
        for (int r = 0; r < 4; ++r) {
            const int row = 4 * lh + r;
            slab[w][row * 64 + ((lr + 16 * os) ^ ((row & 7) << 2))] = oa[os][r];
        }
    __syncthreads();

    // combine m-quarters: warp (wr, ms) sums quarter ms of fg wr's 4 slabs
    {
        const int base = wr * 4;
        const int row  = 4 * ms + lh;     // rows covered by dwords [256ms, 256ms+256)
        const float linv = 1.f / (lsl[base][row] + lsl[base + 1][row] +
                                  lsl[base + 2][row] + lsl[base + 3][row]);
        const int idx = 256 * ms + 4 * l; // lane-consecutive 16B chunks
        f32x4 acc = *(const f32x4*)&slab[base][idx];
        acc += *(const f32x4*)&slab[base + 1][idx];
        acc += *(const f32x4*)&slab[base + 2][idx];
        acc += *(const f32x4*)&slab[base + 3][idx];
        acc *= linv;
        *(f32x4*)&slab[base][idx] = acc;
    }
    __syncthreads();

    // epilogue: warp (wr, is=ms): out = x + bl + Wl * vec (all 8 warps busy)
    {
        const float* D = &slab[wr * 4][0];
        bf16x8 vb0, vb1;
        {
            const f32x4 f0 = *(const f32x4*)&D[lr * 64 + ((8 * lh)      ^ swz)];
            const f32x4 f1 = *(const f32x4*)&D[lr * 64 + ((8 * lh + 4)  ^ swz)];
            const f32x4 f2 = *(const f32x4*)&D[lr * 64 + ((8 * lh + 32) ^ swz)];
            const f32x4 f3 = *(const f32x4*)&D[lr * 64 + ((8 * lh + 36) ^ swz)];
            #pragma unroll
            for (int j = 0; j < 4; ++j) {
                vb0[j] = f2bf(f0[j]); vb0[4 + j] = f2bf(f1[j]);
                vb1[j] = f2bf(f2[j]); vb1[4 + j] = f2bf(f3[j]);
            }
        }
        const int is = ms;
        const float* wp = Wl + (is * 16 + lr) * 64 + lh * 8;
        const f32x4 w0 = *(const f32x4*)(wp + 0);
        const f32x4 w1 = *(const f32x4*)(wp + 4);
        const f32x4 w2 = *(const f32x4*)(wp + 32);
        const f32x4 w3 = *(const f32x4*)(wp + 36);
        bf16x8 wa0, wa1;
        #pragma unroll
        for (int j = 0; j < 4; ++j) {
            wa0[j] = f2bf(w0[j]); wa0[4 + j] = f2bf(w1[j]);
            wa1[j] = f2bf(w2[j]); wa1[4 + j] = f2bf(w3[j]);
        }
        f32x4 od = f32x4{0.f, 0.f, 0.f, 0.f};
        od = MFMA16(wa0, vb0, od);
        od = MFMA16(wa1, vb1, od);
        #pragma unroll
        for (int r = 0; r < 4; ++r) {
            const int i = is * 16 + 4 * lh + r;
            const size_t idx = ((size_t)b * CC + i) * NN + nrow0 + lr;
            out[idx] = x[idx] + bl[i] + od[r];
        }
    }
}

// ---------------------------------------------------------------------------
extern "C" void kernel_launch(void* const* d_in, const int* in_sizes, int n_in,
                              void* d_out, int out_size, void* d_ws, size_t ws_size,
                              hipStream_t stream) {
    const float* x  = (const float*)d_in[0];
    const float* Wk = (const float*)d_in[1];
    const float* bk = (const float*)d_in[2];
    const float* Wq = (const float*)d_in[3];
    const float* bq = (const float*)d_in[4];
    const float* Wv = (const float*)d_in[5];
    const float* bv = (const float*)d_in[6];
    const float* Wl = (const float*)d_in[7];
    const float* bl = (const float*)d_in[8];
    float* out = (float*)d_out;

    const size_t plane = (size_t)BB * NN * CC;  // 2M bf16 elements = 4 MB
    ushort* Kt = (ushort*)d_ws;
    ushort* Qt = Kt + plane;
    ushort* Vo = Qt + plane;

    proj_kernel<<<dim3(BB * (NN / 64)), dim3(512), 0, stream>>>(
        x, Wk, bk, Wq, bq, Wv, bv, Kt, Qt, Vo);
    attn_kernel<<<dim3(BB * (NN / 32)), dim3(512), 0, stream>>>(
        Kt, Qt, Vo, x, Wl, bl, out);
}

// Round 9
// 321.771 us; speedup vs baseline: 1.0624x; 1.0624x over previous
//
#include <hip/hip_runtime.h>
#include <hip/hip_bf16.h>
#include <math.h>

typedef __attribute__((ext_vector_type(8))) short bf16x8;   // 8 bf16 in 4 VGPRs
typedef __attribute__((ext_vector_type(4))) float f32x4;
typedef unsigned short ushort;

#define MFMA16(a, b, c) __builtin_amdgcn_mfma_f32_16x16x32_bf16((a), (b), (c), 0, 0, 0)

constexpr int BB = 8, CC = 64, NN = 4096;
constexpr float LOG2E = 1.4426950408889634f;

__device__ __forceinline__ short f2bf(float f) {
    return __builtin_bit_cast(short, __float2bfloat16(f));   // RNE f32->bf16
}

// ---------------------------------------------------------------------------
// Pass 1 (v2): K/Q/V projections -> bf16.  512 threads, 8 positions/thread.
// Layouts: Kt/Qt [b][n][c] (Kt pre-scaled by log2e), V [b][o][m].
// All global stores coalesced bf16x8.
// ---------------------------------------------------------------------------
__global__ __launch_bounds__(512, 4) void proj_kernel(
    const float* __restrict__ x,
    const float* __restrict__ Wk, const float* __restrict__ bk,
    const float* __restrict__ Wq, const float* __restrict__ bq,
    const float* __restrict__ Wv, const float* __restrict__ bv,
    ushort* __restrict__ Kt, ushort* __restrict__ Qt, ushort* __restrict__ Vo)
{
    __shared__ float xs[64][64];    // [c][pos]
    __shared__ float wkt[64][65];   // [c][o]; reused as K-transpose staging
    __shared__ float wqt[64][65];   // [c][o]; reused as Q-transpose staging
    __shared__ float wvt[64][65];

    const int t   = threadIdx.x;
    const int bid = ((blockIdx.x & 7) << 6) + (blockIdx.x >> 3);  // XCD x -> batch x
    const int b   = bid >> 6;
    const int n0  = (bid & 63) << 6;
    const int o   = t >> 3;   // 0..63 channel
    const int f   = t & 7;    // 0..7 position-octet

    {   // stage x tile (two float4 per thread, coalesced)
        const float* src = x + ((size_t)b * CC + o) * NN + n0 + f * 8;
        *(float4*)&xs[o][f * 8]     = ((const float4*)src)[0];
        *(float4*)&xs[o][f * 8 + 4] = ((const float4*)src)[1];
    }
    {   // stage W transposed: wt[c][o] = W[o][c]
        const float* sk = Wk + o * 64 + f * 8;
        const float* sq = Wq + o * 64 + f * 8;
        const float* sv = Wv + o * 64 + f * 8;
        #pragma unroll
        for (int j = 0; j < 8; ++j) {
            wkt[f * 8 + j][o] = sk[j];
            wqt[f * 8 + j][o] = sq[j];
            wvt[f * 8 + j][o] = sv[j];
        }
    }
    __syncthreads();

    float ak[8], aq[8], av[8];
    {
        const float bkv = bk[o], bqv = bq[o], bvv = bv[o];
        #pragma unroll
        for (int j = 0; j < 8; ++j) { ak[j] = bkv; aq[j] = bqv; av[j] = bvv; }
    }

    #pragma unroll 8
    for (int c = 0; c < 64; ++c) {
        const float wk = wkt[c][o];
        const float wq = wqt[c][o];
        const float wv = wvt[c][o];
        const float4 x0 = *(const float4*)&xs[c][f * 8];
        const float4 x1 = *(const float4*)&xs[c][f * 8 + 4];
        ak[0]=fmaf(wk,x0.x,ak[0]); ak[1]=fmaf(wk,x0.y,ak[1]);
        ak[2]=fmaf(wk,x0.z,ak[2]); ak[3]=fmaf(wk,x0.w,ak[3]);
        ak[4]=fmaf(wk,x1.x,ak[4]); ak[5]=fmaf(wk,x1.y,ak[5]);
        ak[6]=fmaf(wk,x1.z,ak[6]); ak[7]=fmaf(wk,x1.w,ak[7]);
        aq[0]=fmaf(wq,x0.x,aq[0]); aq[1]=fmaf(wq,x0.y,aq[1]);
        aq[2]=fmaf(wq,x0.z,aq[2]); aq[3]=fmaf(wq,x0.w,aq[3]);
        aq[4]=fmaf(wq,x1.x,aq[4]); aq[5]=fmaf(wq,x1.y,aq[5]);
        aq[6]=fmaf(wq,x1.z,aq[6]); aq[7]=fmaf(wq,x1.w,aq[7]);
        av[0]=fmaf(wv,x0.x,av[0]); av[1]=fmaf(wv,x0.y,av[1]);
        av[2]=fmaf(wv,x0.z,av[2]); av[3]=fmaf(wv,x0.w,av[3]);
        av[4]=fmaf(wv,x1.x,av[4]); av[5]=fmaf(wv,x1.y,av[5]);
        av[6]=fmaf(wv,x1.z,av[6]); av[7]=fmaf(wv,x1.w,av[7]);
    }

    // V: coalesced bf16 store [b][o][m]
    {
        bf16x8 v0;
        #pragma unroll
        for (int j = 0; j < 8; ++j) v0[j] = f2bf(av[j]);
        *(bf16x8*)(Vo + ((size_t)b * CC + o) * NN + n0 + f * 8) = v0;
    }

    // K/Q transpose via padded LDS (weights dead), then coalesced stores
    __syncthreads();
    #pragma unroll
    for (int j = 0; j < 8; ++j) {
        wkt[f * 8 + j][o] = ak[j] * LOG2E;   // [pos][c]
        wqt[f * 8 + j][o] = aq[j];
    }
    __syncthreads();
    {
        const int n = t >> 3;   // position row
        const int g = t & 7;    // 8-channel segment
        bf16x8 kv, qv;
        #pragma unroll
        for (int j = 0; j < 8; ++j) {
            kv[j] = f2bf(wkt[n][g * 8 + j]);
            qv[j] = f2bf(wqt[n][g * 8 + j]);
        }
        const size_t base = ((size_t)b * NN + n0 + n) * CC + g * 8;
        *(bf16x8*)(Kt + base) = kv;
        *(bf16x8*)(Qt + base) = qv;
    }
}

// ---------------------------------------------------------------------------
// Pass 2 (v4): flash attention (no-max softmax; scores bounded ~2^12 in log2
// domain) + fused Wl projection + residual.
// 1024 blocks (b, 32-row n-tile), 8 warps: warp w -> (wr = w>>2: 16-row
// fragment group, ms = w&3: m-quarter).  P stored in LDS as bf16
// (XOR-swizzled), unioned with the 4KB f32 O-park slab -> 33KB LDS.
// __launch_bounds__(512, 4): round 8's (512,8) forced VGPR=32 -> massive
// scratch spill (WRITE_SIZE 8->69MB, 2x regression).  Cap 128 lets the
// allocator sit at its natural ~64-84: no spill, 3-4 blocks/CU (24-32
// waves/CU, vs 7 in round 7).
// ---------------------------------------------------------------------------
__global__ __launch_bounds__(512, 4) void attn_kernel(
    const ushort* __restrict__ Kt, const ushort* __restrict__ Qt,
    const ushort* __restrict__ V,  const float* __restrict__ x,
    const float* __restrict__ Wl,  const float* __restrict__ bl,
    float* __restrict__ out)
{
    __shared__ float slab[8][1024];  // per-warp: P(bf16, first 2KB) then O-park(f32)
    __shared__ float lsl[8][16];     // per-warp row sums l

    const int t    = threadIdx.x;
    const int w    = t >> 6;         // 0..7
    const int wr   = w >> 2;         // 0..1 : 16-row fragment group
    const int ms   = w & 3;          // 0..3 : m-quarter
    const int l    = t & 63;
    const int lr   = l & 15;
    const int lh   = l >> 4;
    const int swz  = (lr & 7) << 2;  // f32-index XOR for row=lr slab reads
    const int pswz = (lr & 7) << 3;  // ushort-index XOR for row=lr P reads
    const int bid  = ((blockIdx.x & 7) << 7) + (blockIdx.x >> 3);  // XCD swizzle
    const int b    = bid >> 7;
    const int n0   = (bid & 127) << 5;
    const int nrow0 = n0 + wr * 16;

    ushort* Pb = (ushort*)&slab[w][0];  // 16x64 bf16, swizzled

    // K A-fragments (row = lr, k = 8*lh..+7 / +32), held all kernel
    bf16x8 ka0, ka1;
    {
        const ushort* kp = Kt + ((size_t)b * NN + nrow0 + lr) * CC + lh * 8;
        ka0 = *(const bf16x8*)kp;
        ka1 = *(const bf16x8*)(kp + 32);
    }

    f32x4 oa[4];
    #pragma unroll
    for (int os = 0; os < 4; ++os) oa[os] = f32x4{0.f, 0.f, 0.f, 0.f};
    float lacc[4] = {0.f, 0.f, 0.f, 0.f};

    const ushort* Qb = Qt + (size_t)b * NN * CC;
    const ushort* Vb = V + (size_t)b * CC * NN;

    for (int it = 0; it < 16; ++it) {
        const int m0 = (ms << 10) + (it << 6);

        // S = K^T Q per 16-col subtile -> exp2 -> bf16 P (cvt BEFORE the
        // write: off the read-dependency path)
        #pragma unroll
        for (int s = 0; s < 4; ++s) {
            const ushort* qp = Qb + (size_t)(m0 + s * 16 + lr) * CC + lh * 8;
            const bf16x8 q0 = *(const bf16x8*)qp;
            const bf16x8 q1 = *(const bf16x8*)(qp + 32);
            f32x4 a = f32x4{0.f, 0.f, 0.f, 0.f};
            a = MFMA16(ka0, q0, a);
            a = MFMA16(ka1, q1, a);
            #pragma unroll
            for (int r = 0; r < 4; ++r) {
                const int row = 4 * lh + r;
                const float p = exp2f(a[r]);
                lacc[r] += p;
                Pb[(row * 64 + (lr + 16 * s)) ^ ((row & 7) << 3)] = (ushort)f2bf(p);
            }
        }

        // P A-fragments: row = lr, k = 8*lh (+32); single b128 each
        const bf16x8 pa0 = *(const bf16x8*)&Pb[lr * 64 + ((8 * lh) ^ pswz)];
        const bf16x8 pa1 = *(const bf16x8*)&Pb[lr * 64 + ((8 * lh + 32) ^ pswz)];

        // O += P * V^T
        #pragma unroll
        for (int os = 0; os < 4; ++os) {
            const ushort* vp = Vb + (size_t)(os * 16 + lr) * NN + m0 + lh * 8;
            const bf16x8 v0 = *(const bf16x8*)vp;
            const bf16x8 v1 = *(const bf16x8*)(vp + 32);
            oa[os] = MFMA16(pa0, v0, oa[os]);
            oa[os] = MFMA16(pa1, v1, oa[os]);
        }
    }

    // reduce l over the 16 lr lanes
    #pragma unroll
    for (int r = 0; r < 4; ++r) {
        float v = lacc[r];
        v += __shfl_xor(v, 1);
        v += __shfl_xor(v, 2);
        v += __shfl_xor(v, 4);
        v += __shfl_xor(v, 8);
        lacc[r] = v;
    }
    if (lr == 0) {
        #pragma unroll
        for (int r = 0; r < 4; ++r) lsl[w][4 * lh + r] = lacc[r];
    }

    // park partial O (f32, swizzled D-layout; P region is dead now)
    #pragma unroll
    for (int os = 0; os < 4; ++os)
        #pragma unroll
        for (int r = 0; r < 4; ++r) {
            const int row = 4 * lh + r;
            slab[w][row * 64 + ((lr + 16 * os) ^ ((row & 7) << 2))] = oa[os][r];
        }
    __syncthreads();

    // combine m-quarters: warp (wr, ms) sums quarter ms of fg wr's 4 slabs
    {
        const int base = wr * 4;
        const int row  = 4 * ms + lh;     // rows covered by dwords [256ms, 256ms+256)
        const float linv = 1.f / (lsl[base][row] + lsl[base + 1][row] +
                                  lsl[base + 2][row] + lsl[base + 3][row]);
        const int idx = 256 * ms + 4 * l; // lane-consecutive 16B chunks
        f32x4 acc = *(const f32x4*)&slab[base][idx];
        acc += *(const f32x4*)&slab[base + 1][idx];
        acc += *(const f32x4*)&slab[base + 2][idx];
        acc += *(const f32x4*)&slab[base + 3][idx];
        acc *= linv;
        *(f32x4*)&slab[base][idx] = acc;
    }
    __syncthreads();

    // epilogue: warp (wr, is=ms): out = x + bl + Wl * vec (all 8 warps busy)
    {
        const float* D = &slab[wr * 4][0];
        bf16x8 vb0, vb1;
        {
            const f32x4 f0 = *(const f32x4*)&D[lr * 64 + ((8 * lh)      ^ swz)];
            const f32x4 f1 = *(const f32x4*)&D[lr * 64 + ((8 * lh + 4)  ^ swz)];
            const f32x4 f2 = *(const f32x4*)&D[lr * 64 + ((8 * lh + 32) ^ swz)];
            const f32x4 f3 = *(const f32x4*)&D[lr * 64 + ((8 * lh + 36) ^ swz)];
            #pragma unroll
            for (int j = 0; j < 4; ++j) {
                vb0[j] = f2bf(f0[j]); vb0[4 + j] = f2bf(f1[j]);
                vb1[j] = f2bf(f2[j]); vb1[4 + j] = f2bf(f3[j]);
            }
        }
        const int is = ms;
        const float* wp = Wl + (is * 16 + lr) * 64 + lh * 8;
        const f32x4 w0 = *(const f32x4*)(wp + 0);
        const f32x4 w1 = *(const f32x4*)(wp + 4);
        const f32x4 w2 = *(const f32x4*)(wp + 32);
        const f32x4 w3 = *(const f32x4*)(wp + 36);
        bf16x8 wa0, wa1;
        #pragma unroll
        for (int j = 0; j < 4; ++j) {
            wa0[j] = f2bf(w0[j]); wa0[4 + j] = f2bf(w1[j]);
            wa1[j] = f2bf(w2[j]); wa1[4 + j] = f2bf(w3[j]);
        }
        f32x4 od = f32x4{0.f, 0.f, 0.f, 0.f};
        od = MFMA16(wa0, vb0, od);
        od = MFMA16(wa1, vb1, od);
        #pragma unroll
        for (int r = 0; r < 4; ++r) {
            const int i = is * 16 + 4 * lh + r;
            const size_t idx = ((size_t)b * CC + i) * NN + nrow0 + lr;
            out[idx] = x[idx] + bl[i] + od[r];
        }
    }
}

// ---------------------------------------------------------------------------
extern "C" void kernel_launch(void* const* d_in, const int* in_sizes, int n_in,
                              void* d_out, int out_size, void* d_ws, size_t ws_size,
                              hipStream_t stream) {
    const float* x  = (const float*)d_in[0];
    const float* Wk = (const float*)d_in[1];
    const float* bk = (const float*)d_in[2];
    const float* Wq = (const float*)d_in[3];
    const float* bq = (const float*)d_in[4];
    const float* Wv = (const float*)d_in[5];
    const float* bv = (const float*)d_in[6];
    const float* Wl = (const float*)d_in[7];
    const float* bl = (const float*)d_in[8];
    float* out = (float*)d_out;

    const size_t plane = (size_t)BB * NN * CC;  // 2M bf16 elements = 4 MB
    ushort* Kt = (ushort*)d_ws;
    ushort* Qt = Kt + plane;
    ushort* Vo = Qt + plane;

    proj_kernel<<<dim3(BB * (NN / 64)), dim3(512), 0, stream>>>(
        x, Wk, bk, Wq, bq, Wv, bv, Kt, Qt, Vo);
    attn_kernel<<<dim3(BB * (NN / 32)), dim3(512), 0, stream>>>(
        Kt, Qt, Vo, x, Wl, bl, out);
}

// Round 11
// 224.637 us; speedup vs baseline: 1.5218x; 1.4324x over previous
//
#include <hip/hip_runtime.h>
#include <hip/hip_bf16.h>
#include <math.h>

typedef __attribute__((ext_vector_type(8))) short bf16x8;   // 8 bf16 in 4 VGPRs
typedef __attribute__((ext_vector_type(4))) float f32x4;
typedef unsigned short ushort;

#define MFMA16(a, b, c) __builtin_amdgcn_mfma_f32_16x16x32_bf16((a), (b), (c), 0, 0, 0)

constexpr int BB = 8, CC = 64, NN = 4096;
constexpr float LOG2E = 1.4426950408889634f;

__device__ __forceinline__ short f2bf(float f) {
    return __builtin_bit_cast(short, __float2bfloat16(f));   // RNE f32->bf16
}

// ---------------------------------------------------------------------------
// Pass 1 (v2): K/Q/V projections -> bf16.  512 threads, 8 positions/thread.
// Layouts: Kt/Qt [b][n][c] (Kt pre-scaled by log2e), V [b][o][m].
// All global stores coalesced bf16x8.
// ---------------------------------------------------------------------------
__global__ __launch_bounds__(512, 4) void proj_kernel(
    const float* __restrict__ x,
    const float* __restrict__ Wk, const float* __restrict__ bk,
    const float* __restrict__ Wq, const float* __restrict__ bq,
    const float* __restrict__ Wv, const float* __restrict__ bv,
    ushort* __restrict__ Kt, ushort* __restrict__ Qt, ushort* __restrict__ Vo)
{
    __shared__ float xs[64][64];    // [c][pos]
    __shared__ float wkt[64][65];   // [c][o]; reused as K-transpose staging
    __shared__ float wqt[64][65];   // [c][o]; reused as Q-transpose staging
    __shared__ float wvt[64][65];

    const int t   = threadIdx.x;
    const int bid = ((blockIdx.x & 7) << 6) + (blockIdx.x >> 3);  // XCD x -> batch x
    const int b   = bid >> 6;
    const int n0  = (bid & 63) << 6;
    const int o   = t >> 3;   // 0..63 channel
    const int f   = t & 7;    // 0..7 position-octet

    {   // stage x tile (two float4 per thread, coalesced)
        const float* src = x + ((size_t)b * CC + o) * NN + n0 + f * 8;
        *(float4*)&xs[o][f * 8]     = ((const float4*)src)[0];
        *(float4*)&xs[o][f * 8 + 4] = ((const float4*)src)[1];
    }
    {   // stage W transposed: wt[c][o] = W[o][c]
        const float* sk = Wk + o * 64 + f * 8;
        const float* sq = Wq + o * 64 + f * 8;
        const float* sv = Wv + o * 64 + f * 8;
        #pragma unroll
        for (int j = 0; j < 8; ++j) {
            wkt[f * 8 + j][o] = sk[j];
            wqt[f * 8 + j][o] = sq[j];
            wvt[f * 8 + j][o] = sv[j];
        }
    }
    __syncthreads();

    float ak[8], aq[8], av[8];
    {
        const float bkv = bk[o], bqv = bq[o], bvv = bv[o];
        #pragma unroll
        for (int j = 0; j < 8; ++j) { ak[j] = bkv; aq[j] = bqv; av[j] = bvv; }
    }

    #pragma unroll 8
    for (int c = 0; c < 64; ++c) {
        const float wk = wkt[c][o];
        const float wq = wqt[c][o];
        const float wv = wvt[c][o];
        const float4 x0 = *(const float4*)&xs[c][f * 8];
        const float4 x1 = *(const float4*)&xs[c][f * 8 + 4];
        ak[0]=fmaf(wk,x0.x,ak[0]); ak[1]=fmaf(wk,x0.y,ak[1]);
        ak[2]=fmaf(wk,x0.z,ak[2]); ak[3]=fmaf(wk,x0.w,ak[3]);
        ak[4]=fmaf(wk,x1.x,ak[4]); ak[5]=fmaf(wk,x1.y,ak[5]);
        ak[6]=fmaf(wk,x1.z,ak[6]); ak[7]=fmaf(wk,x1.w,ak[7]);
        aq[0]=fmaf(wq,x0.x,aq[0]); aq[1]=fmaf(wq,x0.y,aq[1]);
        aq[2]=fmaf(wq,x0.z,aq[2]); aq[3]=fmaf(wq,x0.w,aq[3]);
        aq[4]=fmaf(wq,x1.x,aq[4]); aq[5]=fmaf(wq,x1.y,aq[5]);
        aq[6]=fmaf(wq,x1.z,aq[6]); aq[7]=fmaf(wq,x1.w,aq[7]);
        av[0]=fmaf(wv,x0.x,av[0]); av[1]=fmaf(wv,x0.y,av[1]);
        av[2]=fmaf(wv,x0.z,av[2]); av[3]=fmaf(wv,x0.w,av[3]);
        av[4]=fmaf(wv,x1.x,av[4]); av[5]=fmaf(wv,x1.y,av[5]);
        av[6]=fmaf(wv,x1.z,av[6]); av[7]=fmaf(wv,x1.w,av[7]);
    }

    // V: coalesced bf16 store [b][o][m]
    {
        bf16x8 v0;
        #pragma unroll
        for (int j = 0; j < 8; ++j) v0[j] = f2bf(av[j]);
        *(bf16x8*)(Vo + ((size_t)b * CC + o) * NN + n0 + f * 8) = v0;
    }

    // K/Q transpose via padded LDS (weights dead), then coalesced stores
    __syncthreads();
    #pragma unroll
    for (int j = 0; j < 8; ++j) {
        wkt[f * 8 + j][o] = ak[j] * LOG2E;   // [pos][c]
        wqt[f * 8 + j][o] = aq[j];
    }
    __syncthreads();
    {
        const int n = t >> 3;   // position row
        const int g = t & 7;    // 8-channel segment
        bf16x8 kv, qv;
        #pragma unroll
        for (int j = 0; j < 8; ++j) {
            kv[j] = f2bf(wkt[n][g * 8 + j]);
            qv[j] = f2bf(wqt[n][g * 8 + j]);
        }
        const size_t base = ((size_t)b * NN + n0 + n) * CC + g * 8;
        *(bf16x8*)(Kt + base) = kv;
        *(bf16x8*)(Qt + base) = qv;
    }
}

// ---------------------------------------------------------------------------
// Pass 2 (v5 = round-7 structure + launch_bounds fix): flash attention
// (no-max softmax) + fused Wl projection + residual.
// 512 blocks (b, 64-row n-tile), 8 warps: warp w -> (wr = w>>2: 32-row group,
// ms = w&3: m-quarter).  Each warp: 2 x 16-row fragment groups -> 32 MFMA per
// 16 global loads per iter (r9's 16-row variant halved this ratio and
// regressed 137->249us while RAISING occupancy: the kernel is latency-bound
// on L2 Q/V loads, so arithmetic-per-load is what matters).
// __launch_bounds__(512,4): r7's (512,3) capped residency at 1 block/CU
// (21.6% occupancy); 65KB LDS and 84 VGPR both permit 2 blocks/CU.
// ---------------------------------------------------------------------------
__global__ __launch_bounds__(512, 4) void attn_kernel(
    const ushort* __restrict__ Kt, const ushort* __restrict__ Qt,
    const ushort* __restrict__ V,  const float* __restrict__ x,
    const float* __restrict__ Wl,  const float* __restrict__ bl,
    float* __restrict__ out)
{
    __shared__ float slab[8][2][1024];  // per (warp, fg): P buffer, then O partial
    __shared__ float lsl[8][2][16];     // per (warp, fg): row sums l

    const int t   = threadIdx.x;
    const int w   = t >> 6;          // 0..7
    const int wr  = w >> 2;          // 0..1 : 32-row group
    const int ms  = w & 3;           // 0..3 : m-split
    const int l   = t & 63;
    const int lr  = l & 15;
    const int lh  = l >> 4;
    const int swz = (lr & 7) << 2;   // float-index XOR for row=lr LDS reads
    const int bid = ((blockIdx.x & 7) << 6) + (blockIdx.x >> 3);  // XCD swizzle
    const int b   = bid >> 6;
    const int n0  = (bid & 63) << 6;
    const int nrow0 = n0 + wr * 32;

    float* P0 = &slab[w][0][0];
    float* P1 = &slab[w][1][0];

    // K A-fragments for both 16-row groups, held all kernel
    bf16x8 ka[2][2];
    #pragma unroll
    for (int fg = 0; fg < 2; ++fg) {
        const ushort* kp = Kt + ((size_t)b * NN + nrow0 + fg * 16 + lr) * CC + lh * 8;
        ka[fg][0] = *(const bf16x8*)kp;
        ka[fg][1] = *(const bf16x8*)(kp + 32);
    }

    f32x4 oa[2][4];
    #pragma unroll
    for (int fg = 0; fg < 2; ++fg)
        #pragma unroll
        for (int os = 0; os < 4; ++os) oa[fg][os] = f32x4{0.f, 0.f, 0.f, 0.f};
    float lacc[2][4];
    #pragma unroll
    for (int fg = 0; fg < 2; ++fg)
        #pragma unroll
        for (int r = 0; r < 4; ++r) lacc[fg][r] = 0.f;

    const ushort* Qb = Qt + (size_t)b * NN * CC;
    const ushort* Vb = V + (size_t)b * CC * NN;

    for (int it = 0; it < 16; ++it) {
        const int m0 = (ms << 10) + (it << 6);

        // S phase per 16-col subtile: QK MFMAs -> exp2 -> P slab
        #pragma unroll
        for (int s = 0; s < 4; ++s) {
            const ushort* qp = Qb + (size_t)(m0 + s * 16 + lr) * CC + lh * 8;
            const bf16x8 q0 = *(const bf16x8*)qp;
            const bf16x8 q1 = *(const bf16x8*)(qp + 32);
            f32x4 a0 = f32x4{0.f, 0.f, 0.f, 0.f};
            f32x4 a1 = f32x4{0.f, 0.f, 0.f, 0.f};
            a0 = MFMA16(ka[0][0], q0, a0);
            a0 = MFMA16(ka[0][1], q1, a0);
            a1 = MFMA16(ka[1][0], q0, a1);
            a1 = MFMA16(ka[1][1], q1, a1);
            #pragma unroll
            for (int r = 0; r < 4; ++r) {
                const int row = 4 * lh + r;
                const int col = (lr + 16 * s) ^ ((row & 7) << 2);
                const float p0 = exp2f(a0[r]);
                const float p1 = exp2f(a1[r]);
                lacc[0][r] += p0;
                lacc[1][r] += p1;
                P0[row * 64 + col] = p0;
                P1[row * 64 + col] = p1;
            }
        }

        // P A-fragments (row = lr, k = 8*lh + 32*ks)
        bf16x8 pa[2][2];
        #pragma unroll
        for (int fg = 0; fg < 2; ++fg) {
            const float* P = fg ? P1 : P0;
            #pragma unroll
            for (int ks = 0; ks < 2; ++ks) {
                const int c0 = 8 * lh + 32 * ks;
                const f32x4 f0 = *(const f32x4*)&P[lr * 64 + ((c0 + 0) ^ swz)];
                const f32x4 f1 = *(const f32x4*)&P[lr * 64 + ((c0 + 4) ^ swz)];
                bf16x8 tmp;
                #pragma unroll
                for (int j = 0; j < 4; ++j) { tmp[j] = f2bf(f0[j]); tmp[4 + j] = f2bf(f1[j]); }
                pa[fg][ks] = tmp;
            }
        }

        // PV: V B-frags shared by both row groups
        #pragma unroll
        for (int os = 0; os < 4; ++os) {
            const ushort* vp = Vb + (size_t)(os * 16 + lr) * NN + m0 + lh * 8;
            const bf16x8 v0 = *(const bf16x8*)vp;
            const bf16x8 v1 = *(const bf16x8*)(vp + 32);
            oa[0][os] = MFMA16(pa[0][0], v0, oa[0][os]);
            oa[0][os] = MFMA16(pa[0][1], v1, oa[0][os]);
            oa[1][os] = MFMA16(pa[1][0], v0, oa[1][os]);
            oa[1][os] = MFMA16(pa[1][1], v1, oa[1][os]);
        }
    }

    // reduce l over the 16 lr lanes (once, not per iter)
    #pragma unroll
    for (int fg = 0; fg < 2; ++fg)
        #pragma unroll
        for (int r = 0; r < 4; ++r) {
            float v = lacc[fg][r];
            v += __shfl_xor(v, 1);
            v += __shfl_xor(v, 2);
            v += __shfl_xor(v, 4);
            v += __shfl_xor(v, 8);
            lacc[fg][r] = v;
        }
    if (lr == 0) {
        #pragma unroll
        for (int fg = 0; fg < 2; ++fg)
            #pragma unroll
            for (int r = 0; r < 4; ++r)
                lsl[w][fg][4 * lh + r] = lacc[fg][r];
    }

    // park partial O into slabs (swizzled D-layout positions, same as P)
    #pragma unroll
    for (int fg = 0; fg < 2; ++fg) {
        float* P = fg ? P1 : P0;
        #pragma unroll
        for (int os = 0; os < 4; ++os)
            #pragma unroll
            for (int r = 0; r < 4; ++r) {
                const int row = 4 * lh + r;
                P[row * 64 + ((lr + 16 * os) ^ ((row & 7) << 2))] = oa[fg][os][r];
            }
    }
    __syncthreads();
    if (ms != 0) return;

    // ---- combine m-splits (warps w = wr*4): raw elementwise sum of the 4
    // slabs (swizzle is within-row, so row = idx>>6 for the 1/l scale)
    #pragma unroll
    for (int fg = 0; fg < 2; ++fg) {
        float linv[4];
        #pragma unroll
        for (int k = 0; k < 4; ++k) {
            const int row = 4 * k + lh;
            linv[k] = 1.f / (lsl[w][fg][row] + lsl[w + 1][fg][row] +
                             lsl[w + 2][fg][row] + lsl[w + 3][fg][row]);
        }
        float* D = &slab[w][fg][0];
        #pragma unroll
        for (int k = 0; k < 4; ++k) {
            const int idx = 256 * k + 4 * l;   // lane-consecutive 16B chunks
            f32x4 acc = *(const f32x4*)&slab[w][fg][idx];
            acc += *(const f32x4*)&slab[w + 1][fg][idx];
            acc += *(const f32x4*)&slab[w + 2][fg][idx];
            acc += *(const f32x4*)&slab[w + 3][fg][idx];
            acc *= linv[k];
            *(f32x4*)&D[idx] = acc;
        }
    }

    // ---- epilogue: out = x + bl + Wl * vec, per 16-row fragment group
    #pragma unroll
    for (int fg = 0; fg < 2; ++fg) {
        const float* P = &slab[w][fg][0];
        const int nr = nrow0 + fg * 16;

        bf16x8 vb[2];
        #pragma unroll
        for (int ks = 0; ks < 2; ++ks) {
            const int c0 = 8 * lh + 32 * ks;
            const f32x4 f0 = *(const f32x4*)&P[lr * 64 + ((c0 + 0) ^ swz)];
            const f32x4 f1 = *(const f32x4*)&P[lr * 64 + ((c0 + 4) ^ swz)];
            bf16x8 tmp;
            #pragma unroll
            for (int j = 0; j < 4; ++j) { tmp[j] = f2bf(f0[j]); tmp[4 + j] = f2bf(f1[j]); }
            vb[ks] = tmp;
        }

        #pragma unroll
        for (int is = 0; is < 4; ++is) {
            const float* wp = Wl + (is * 16 + lr) * 64 + lh * 8;
            const f32x4 w0 = *(const f32x4*)(wp + 0);
            const f32x4 w1 = *(const f32x4*)(wp + 4);
            const f32x4 w2 = *(const f32x4*)(wp + 32);
            const f32x4 w3 = *(const f32x4*)(wp + 36);
            bf16x8 wa0, wa1;
            #pragma unroll
            for (int j = 0; j < 4; ++j) {
                wa0[j] = f2bf(w0[j]); wa0[4 + j] = f2bf(w1[j]);
                wa1[j] = f2bf(w2[j]); wa1[4 + j] = f2bf(w3[j]);
            }
            f32x4 od = f32x4{0.f, 0.f, 0.f, 0.f};
            od = MFMA16(wa0, vb[0], od);
            od = MFMA16(wa1, vb[1], od);
            #pragma unroll
            for (int r = 0; r < 4; ++r) {
                const int i = is * 16 + 4 * lh + r;
                const size_t idx = ((size_t)b * CC + i) * NN + nr + lr;
                out[idx] = x[idx] + bl[i] + od[r];
            }
        }
    }
}

// ---------------------------------------------------------------------------
extern "C" void kernel_launch(void* const* d_in, const int* in_sizes, int n_in,
                              void* d_out, int out_size, void* d_ws, size_t ws_size,
                              hipStream_t stream) {
    const float* x  = (const float*)d_in[0];
    const float* Wk = (const float*)d_in[1];
    const float* bk = (const float*)d_in[2];
    const float* Wq = (const float*)d_in[3];
    const float* bq = (const float*)d_in[4];
    const float* Wv = (const float*)d_in[5];
    const float* bv = (const float*)d_in[6];
    const float* Wl = (const float*)d_in[7];
    const float* bl = (const float*)d_in[8];
    float* out = (float*)d_out;

    const size_t plane = (size_t)BB * NN * CC;  // 2M bf16 elements = 4 MB
    ushort* Kt = (ushort*)d_ws;
    ushort* Qt = Kt + plane;
    ushort* Vo = Qt + plane;

    proj_kernel<<<dim3(BB * (NN / 64)), dim3(512), 0, stream>>>(
        x, Wk, bk, Wq, bq, Wv, bv, Kt, Qt, Vo);
    attn_kernel<<<dim3(BB * (NN / 64)), dim3(512), 0, stream>>>(
        Kt, Qt, Vo, x, Wl, bl, out);
}